// Round 9
// baseline (557.237 us; speedup 1.0000x reference)
//
#include <hip/hip_runtime.h>
#include <hip/hip_bf16.h>

#define NN 50000
#define NE 400000
#define DIN 128
#define DH 32
#define NH 10
#define HID 320
#define DOUT 32
#define NEG_SLOPE 0.2f
#define EPS_BN 1e-5f

typedef __attribute__((ext_vector_type(8))) short short8;
typedef __attribute__((ext_vector_type(4))) float f32x4;

__device__ inline unsigned short f2bf(float f) {
    unsigned int u = __float_as_uint(f);
    u += 0x7fffu + ((u >> 16) & 1u);
    return (unsigned short)(u >> 16);
}
__device__ inline float bf2f(unsigned short u) {
    return __uint_as_float(((unsigned int)u) << 16);
}
__device__ inline float bflo(unsigned int u) { return __uint_as_float(u << 16); }
__device__ inline float bfhi(unsigned int u) { return __uint_as_float(u & 0xffff0000u); }
__device__ inline float lrelu(float x) { return fmaxf(x, NEG_SLOPE * x); }

// ---------------- precasts ----------------
__global__ __launch_bounds__(256) void precast_x(const float* __restrict__ x,
        unsigned short* __restrict__ xb) {
    int i = blockIdx.x * 256 + threadIdx.x;          // over NN*DIN/4
    if (i < NN * DIN / 4) {
        float4 v = *(const float4*)(x + (size_t)i * 4);
        ushort4 s;
        s.x = f2bf(v.x); s.y = f2bf(v.y); s.z = f2bf(v.z); s.w = f2bf(v.w);
        *(ushort4*)(xb + (size_t)i * 4) = s;
    }
}

__global__ void precast_w1(const float* __restrict__ Wl, const float* __restrict__ Wr,
        unsigned short* __restrict__ wlt, unsigned short* __restrict__ wrt) {
    int idx = blockIdx.x * 256 + threadIdx.x;        // over HID*DIN = 40960
    if (idx < HID * DIN) {
        int c = idx >> 7, k = idx & 127;
        wlt[idx] = f2bf(Wl[(size_t)k * HID + c]);
        wrt[idx] = f2bf(Wr[(size_t)k * HID + c]);
    }
}

__global__ void precast_w2(const float* __restrict__ Wl2, const float* __restrict__ Wr2,
        unsigned short* __restrict__ wl2t, unsigned short* __restrict__ wr2t) {
    int idx = blockIdx.x * 256 + threadIdx.x;        // over HID*DOUT = 10240
    if (idx < HID * DOUT) {
        int c = idx / HID, k = idx - c * HID;
        wl2t[idx] = f2bf(Wl2[k * DOUT + c]);
        wr2t[idx] = f2bf(Wr2[k * DOUT + c]);
    }
}

// ---------------- GEMM1 (MFMA bf16, LDS-free): xb[NN,128] @ W^T -> bf16 xl1, xr1 --------
// 1D grid 7820 = 782 row-tiles x 10 col-tiles; XCD-chunked so a row-tile's 10
// col-tiles run consecutively on ONE XCD (L2 reuse of the A-panel).
__global__ __launch_bounds__(256) void gemm1_kernel(
    const unsigned short* __restrict__ xb,
    const unsigned short* __restrict__ wlt, const unsigned short* __restrict__ wrt,
    const float* __restrict__ bl, const float* __restrict__ br,
    unsigned short* __restrict__ xl1, unsigned short* __restrict__ xr1)
{
    // bijective XCD chunking: 7820 = 8*977+4 -> xcd<4 own 978 tiles, else 977
    int b = blockIdx.x;
    int xcd = b & 7, j = b >> 3;
    int base = (xcd < 4) ? xcd * 978 : 3912 + (xcd - 4) * 977;
    int t = base + j;
    int r0 = (t / 10) * 64;
    int c0 = (t % 10) * 32;

    const int w = threadIdx.x >> 6, lane = threadIdx.x & 63;
    const int row16 = lane & 15;
    const int kgrp = (lane >> 4) << 3;
    const int arow = r0 + w * 16 + row16;
    const int arow_c = min(arow, NN - 1);
    const unsigned short* ap  = xb  + (size_t)arow_c * DIN + kgrp;
    const unsigned short* bLp = wlt + (size_t)(c0 + row16) * DIN + kgrp;
    const unsigned short* bRp = wrt + (size_t)(c0 + row16) * DIN + kgrp;

    f32x4 acc00 = {}, acc01 = {}, acc10 = {}, acc11 = {};
    #pragma unroll
    for (int kk = 0; kk < 4; ++kk) {
        short8 a   = *(const short8*)(ap + kk * 32);
        short8 bL0 = *(const short8*)(bLp + kk * 32);
        short8 bL1 = *(const short8*)(bLp + 16 * DIN + kk * 32);
        short8 bR0 = *(const short8*)(bRp + kk * 32);
        short8 bR1 = *(const short8*)(bRp + 16 * DIN + kk * 32);
        acc00 = __builtin_amdgcn_mfma_f32_16x16x32_bf16(a, bL0, acc00, 0, 0, 0);
        acc01 = __builtin_amdgcn_mfma_f32_16x16x32_bf16(a, bL1, acc01, 0, 0, 0);
        acc10 = __builtin_amdgcn_mfma_f32_16x16x32_bf16(a, bR0, acc10, 0, 0, 0);
        acc11 = __builtin_amdgcn_mfma_f32_16x16x32_bf16(a, bR1, acc11, 0, 0, 0);
    }
    const int orow = r0 + w * 16 + ((lane >> 4) << 2);
    #pragma unroll
    for (int cf = 0; cf < 2; ++cf) {
        const int col = c0 + cf * 16 + row16;
        const float blv = bl[col], brv = br[col];
        const f32x4 aL = cf ? acc01 : acc00;
        const f32x4 aR = cf ? acc11 : acc10;
        #pragma unroll
        for (int reg = 0; reg < 4; ++reg) {
            int row = orow + reg;
            if (row < NN) {
                xl1[(size_t)row * HID + col] = f2bf(aL[reg] + blv);
                xr1[(size_t)row * HID + col] = f2bf(aR[reg] + brv);
            }
        }
    }
}

// ---------------- CSR build ----------------
__global__ void hist_kernel(const int* __restrict__ dst, int* __restrict__ deg) {
    int e = blockIdx.x * blockDim.x + threadIdx.x;
    if (e < NE) atomicAdd(&deg[dst[e]], 1);
}

// 3-phase hierarchical scan: 49 blocks x 1024
__global__ __launch_bounds__(1024) void scan1_kernel(const int* __restrict__ deg,
        int* __restrict__ tmp, int* __restrict__ bsum) {
    __shared__ int s[1024];
    const int tid = threadIdx.x;
    int i = blockIdx.x * 1024 + tid;
    int v = (i < NN) ? deg[i] : 0;
    s[tid] = v;
    __syncthreads();
    for (int off = 1; off < 1024; off <<= 1) {
        int u = (tid >= off) ? s[tid - off] : 0;
        __syncthreads();
        s[tid] += u;
        __syncthreads();
    }
    if (i < NN) tmp[i] = s[tid];
    if (tid == 1023) bsum[blockIdx.x] = s[1023];
}

__global__ void scan2_kernel(const int* __restrict__ bsum, int* __restrict__ boff) {
    int lane = threadIdx.x;                  // 64 threads, 1 wave
    int v = (lane < 49) ? bsum[lane] : 0;
    for (int off = 1; off < 64; off <<= 1) {
        int u = __shfl_up(v, off);
        if (lane >= off) v += u;
    }
    int excl = __shfl_up(v, 1);
    if (lane == 0) excl = 0;
    if (lane < 49) boff[lane] = excl;
}

__global__ __launch_bounds__(1024) void scan3_kernel(const int* __restrict__ deg,
        const int* __restrict__ tmp, const int* __restrict__ boff,
        int* __restrict__ row_ptr, int* __restrict__ cursor) {
    int i = blockIdx.x * 1024 + threadIdx.x;
    if (i < NN) {
        int incl = tmp[i] + boff[blockIdx.x];
        int st = incl - deg[i];
        row_ptr[i] = st;
        cursor[i] = st;
        if (i == NN - 1) row_ptr[NN] = incl;
    }
}

__global__ void scatter_kernel(const int* __restrict__ src, const int* __restrict__ dst,
        int* __restrict__ cursor, int* __restrict__ sorted_src) {
    int e = blockIdx.x * blockDim.x + threadIdx.x;
    if (e < NE) {
        int d = dst[e];
        int p = atomicAdd(&cursor[d], 1);
        sorted_src[p] = src[e];
    }
}

// ---------------- Layer-1 aggregation: 4 nodes/block, 8 lanes/head, 4 ch/lane -----------
__global__ __launch_bounds__(320) void agg1_kernel(
    const unsigned short* __restrict__ xl1, const unsigned short* __restrict__ xr1,
    const int* __restrict__ row_ptr, const int* __restrict__ sorted_src,
    const float* __restrict__ att1, const float* __restrict__ bias1,
    unsigned short* __restrict__ h1b)
{
    const int t = threadIdx.x;
    const int nsub = t / 80;
    const int r = t - nsub * 80;
    const int h = r >> 3;
    const int l8 = r & 7;
    const int c0 = h * 32 + l8 * 4;
    const int n = blockIdx.x * 4 + nsub;

    const float4 at = *(const float4*)(att1 + c0);
    const unsigned rbase = (unsigned)n * HID + c0;
    uint2 xr4 = *(const uint2*)(xr1 + rbase);
    const float xr0 = bflo(xr4.x), xr1f = bfhi(xr4.x);
    const float xr2 = bflo(xr4.y), xr3 = bfhi(xr4.y);

    const int rp = row_ptr[n];
    const int deg = row_ptr[n + 1] - rp;
    const int* sp = sorted_src + rp;

    float l = 0.f, ac0 = 0.f, ac1 = 0.f, ac2 = 0.f, ac3 = 0.f;
    int i = 0;
    for (; i + 2 <= deg; i += 2) {
        unsigned offA = (unsigned)sp[i] * HID + c0;
        unsigned offB = (unsigned)sp[i + 1] * HID + c0;
        uint2 ua = *(const uint2*)(xl1 + offA);
        uint2 ub = *(const uint2*)(xl1 + offB);
        float xA0 = bflo(ua.x), xA1 = bfhi(ua.x), xA2 = bflo(ua.y), xA3 = bfhi(ua.y);
        float xB0 = bflo(ub.x), xB1 = bfhi(ub.x), xB2 = bflo(ub.y), xB3 = bfhi(ub.y);
        float vA = lrelu(xA0 + xr0) * at.x;
        vA = fmaf(lrelu(xA1 + xr1f), at.y, vA);
        vA = fmaf(lrelu(xA2 + xr2), at.z, vA);
        vA = fmaf(lrelu(xA3 + xr3), at.w, vA);
        float vB = lrelu(xB0 + xr0) * at.x;
        vB = fmaf(lrelu(xB1 + xr1f), at.y, vB);
        vB = fmaf(lrelu(xB2 + xr2), at.z, vB);
        vB = fmaf(lrelu(xB3 + xr3), at.w, vB);
        vA += __shfl_xor(vA, 1); vB += __shfl_xor(vB, 1);
        vA += __shfl_xor(vA, 2); vB += __shfl_xor(vB, 2);
        vA += __shfl_xor(vA, 4); vB += __shfl_xor(vB, 4);
        float pA = __expf(vA), pB = __expf(vB);
        l += pA + pB;
        ac0 = fmaf(pA, xA0, ac0); ac0 = fmaf(pB, xB0, ac0);
        ac1 = fmaf(pA, xA1, ac1); ac1 = fmaf(pB, xB1, ac1);
        ac2 = fmaf(pA, xA2, ac2); ac2 = fmaf(pB, xB2, ac2);
        ac3 = fmaf(pA, xA3, ac3); ac3 = fmaf(pB, xB3, ac3);
    }
    if (i < deg) {
        unsigned offA = (unsigned)sp[i] * HID + c0;
        uint2 ua = *(const uint2*)(xl1 + offA);
        float xA0 = bflo(ua.x), xA1 = bfhi(ua.x), xA2 = bflo(ua.y), xA3 = bfhi(ua.y);
        float vA = lrelu(xA0 + xr0) * at.x;
        vA = fmaf(lrelu(xA1 + xr1f), at.y, vA);
        vA = fmaf(lrelu(xA2 + xr2), at.z, vA);
        vA = fmaf(lrelu(xA3 + xr3), at.w, vA);
        vA += __shfl_xor(vA, 1);
        vA += __shfl_xor(vA, 2);
        vA += __shfl_xor(vA, 4);
        float pA = __expf(vA);
        l += pA;
        ac0 = fmaf(pA, xA0, ac0); ac1 = fmaf(pA, xA1, ac1);
        ac2 = fmaf(pA, xA2, ac2); ac3 = fmaf(pA, xA3, ac3);
    }
    const float inv = 1.f / (l + 1e-16f);
    const float4 bi = *(const float4*)(bias1 + c0);
    uint2 outp;
    outp.x = (unsigned)f2bf(ac0 * inv + bi.x) | ((unsigned)f2bf(ac1 * inv + bi.y) << 16);
    outp.y = (unsigned)f2bf(ac2 * inv + bi.z) | ((unsigned)f2bf(ac3 * inv + bi.w) << 16);
    *(uint2*)(h1b + rbase) = outp;
}

// ---------------- BatchNorm stats (vectorized) / finalize ----------------
__global__ __launch_bounds__(320) void bnstats_kernel(const unsigned short* __restrict__ h1b,
        double* __restrict__ bn_sum, double* __restrict__ bn_sq) {
    const int tid = threadIdx.x;
    const int q = tid / 80;               // 0..3 row-quarter
    const int c4 = (tid - q * 80) * 4;    // 0..316
    double s0 = 0, s1 = 0, s2 = 0, s3 = 0, q0 = 0, q1 = 0, q2 = 0, q3 = 0;
    for (int n = blockIdx.x * 4 + q; n < NN; n += gridDim.x * 4) {
        uint2 hv = *(const uint2*)(h1b + (size_t)n * HID + c4);
        float v0 = bflo(hv.x), v1 = bfhi(hv.x), v2 = bflo(hv.y), v3 = bfhi(hv.y);
        s0 += v0; q0 += (double)v0 * v0;
        s1 += v1; q1 += (double)v1 * v1;
        s2 += v2; q2 += (double)v2 * v2;
        s3 += v3; q3 += (double)v3 * v3;
    }
    atomicAdd(&bn_sum[c4 + 0], s0); atomicAdd(&bn_sq[c4 + 0], q0);
    atomicAdd(&bn_sum[c4 + 1], s1); atomicAdd(&bn_sq[c4 + 1], q1);
    atomicAdd(&bn_sum[c4 + 2], s2); atomicAdd(&bn_sq[c4 + 2], q2);
    atomicAdd(&bn_sum[c4 + 3], s3); atomicAdd(&bn_sq[c4 + 3], q3);
}

__global__ void bnfinal_kernel(const double* __restrict__ bn_sum, const double* __restrict__ bn_sq,
        const float* __restrict__ gamma, const float* __restrict__ beta,
        float* __restrict__ scale, float* __restrict__ shift) {
    int c = threadIdx.x;
    double mean = bn_sum[c] / (double)NN;
    double var  = bn_sq[c] / (double)NN - mean * mean;
    float sc = gamma[c] * rsqrtf((float)var + EPS_BN);
    scale[c] = sc;
    shift[c] = beta[c] - (float)mean * sc;
}

// ---------------- GEMM2 (MFMA bf16) fused BN+PReLU: h[NN,320] @ [320,32] -> xl2, xr2 -----
__global__ __launch_bounds__(256) void gemm2_kernel(
    const unsigned short* __restrict__ h1b,
    const float* __restrict__ scale, const float* __restrict__ shift,
    const float* __restrict__ prelu_a,
    const unsigned short* __restrict__ wl2t, const unsigned short* __restrict__ wr2t,
    const float* __restrict__ bl2, const float* __restrict__ br2,
    float* __restrict__ xl2, float* __restrict__ xr2)
{
    __shared__ short hs[64 * 320];   // transformed rows, bf16, XOR-swizzled
    const int tid = threadIdx.x;
    const int r0 = blockIdx.x * 64;
    const float a = prelu_a[0];
    for (int f = tid; f < 5120; f += 256) {
        int e = f << 2;
        int rr = e / 320;
        int cc = e - rr * 320;
        ushort4 hv = make_ushort4(0, 0, 0, 0);
        if (r0 + rr < NN) hv = *(const ushort4*)(h1b + (size_t)(r0 + rr) * HID + cc);
        float4 sc = *(const float4*)(scale + cc);
        float4 sh = *(const float4*)(shift + cc);
        float o0 = bf2f(hv.x) * sc.x + sh.x; o0 = (o0 >= 0.f) ? o0 : a * o0;
        float o1 = bf2f(hv.y) * sc.y + sh.y; o1 = (o1 >= 0.f) ? o1 : a * o1;
        float o2 = bf2f(hv.z) * sc.z + sh.z; o2 = (o2 >= 0.f) ? o2 : a * o2;
        float o3 = bf2f(hv.w) * sc.w + sh.w; o3 = (o3 >= 0.f) ? o3 : a * o3;
        short4 s;
        s.x = (short)f2bf(o0); s.y = (short)f2bf(o1);
        s.z = (short)f2bf(o2); s.w = (short)f2bf(o3);
        int u = (rr * 320 + cc) ^ ((rr & 7) << 3);
        *(short4*)&hs[u] = s;
    }
    __syncthreads();

    const int w = tid >> 6, lane = tid & 63;
    const int arow = w * 16 + (lane & 15);
    const int kgrp = (lane >> 4) << 3;
    const int bcol = lane & 15;
    f32x4 acc00 = {}, acc01 = {}, acc10 = {}, acc11 = {};
    #pragma unroll
    for (int kk = 0; kk < 10; ++kk) {
        int au = (arow * 320 + kk * 32 + kgrp) ^ ((arow & 7) << 3);
        short8 afr = *(short8*)&hs[au];
        const int ko = kk * 32 + kgrp;
        short8 bL0 = *(const short8*)(wl2t + bcol * HID + ko);
        short8 bL1 = *(const short8*)(wl2t + (16 + bcol) * HID + ko);
        short8 bR0 = *(const short8*)(wr2t + bcol * HID + ko);
        short8 bR1 = *(const short8*)(wr2t + (16 + bcol) * HID + ko);
        acc00 = __builtin_amdgcn_mfma_f32_16x16x32_bf16(afr, bL0, acc00, 0, 0, 0);
        acc01 = __builtin_amdgcn_mfma_f32_16x16x32_bf16(afr, bL1, acc01, 0, 0, 0);
        acc10 = __builtin_amdgcn_mfma_f32_16x16x32_bf16(afr, bR0, acc10, 0, 0, 0);
        acc11 = __builtin_amdgcn_mfma_f32_16x16x32_bf16(afr, bR1, acc11, 0, 0, 0);
    }
    const int orow = r0 + w * 16 + ((lane >> 4) << 2);
    #pragma unroll
    for (int cf = 0; cf < 2; ++cf) {
        const int col = cf * 16 + bcol;
        const float blv = bl2[col], brv = br2[col];
        const f32x4 aL = cf ? acc01 : acc00;
        const f32x4 aR = cf ? acc11 : acc10;
        #pragma unroll
        for (int reg = 0; reg < 4; ++reg) {
            int row = orow + reg;
            if (row < NN) {
                xl2[(size_t)row * DOUT + col] = aL[reg] + blv;
                xr2[(size_t)row * DOUT + col] = aR[reg] + brv;
            }
        }
    }
}

// ---------------- Layer-2 aggregation: 32 nodes/block, 8 lanes/node, 4 ch/lane ----------
__global__ __launch_bounds__(256) void agg2_kernel(
    const float* __restrict__ xl2, const float* __restrict__ xr2,
    const int* __restrict__ row_ptr, const int* __restrict__ sorted_src,
    const float* __restrict__ att2, const float* __restrict__ bias2,
    float* __restrict__ out)
{
    const int t = threadIdx.x;
    const int nsub = t >> 3;
    const int l8 = t & 7;
    const int c0 = l8 * 4;
    const int n = blockIdx.x * 32 + nsub;
    if (n >= NN) return;

    const float4 at = *(const float4*)(att2 + c0);
    const float4 xr4 = *(const float4*)(xr2 + (size_t)n * DOUT + c0);
    const int rp = row_ptr[n];
    const int deg = row_ptr[n + 1] - rp;
    const int* sp = sorted_src + rp;

    float l = 0.f, ac0 = 0.f, ac1 = 0.f, ac2 = 0.f, ac3 = 0.f;
    int i = 0;
    for (; i + 2 <= deg; i += 2) {
        unsigned offA = (unsigned)sp[i] * DOUT + c0;
        unsigned offB = (unsigned)sp[i + 1] * DOUT + c0;
        float4 xa = *(const float4*)(xl2 + offA);
        float4 xb = *(const float4*)(xl2 + offB);
        float vA = lrelu(xa.x + xr4.x) * at.x;
        vA = fmaf(lrelu(xa.y + xr4.y), at.y, vA);
        vA = fmaf(lrelu(xa.z + xr4.z), at.z, vA);
        vA = fmaf(lrelu(xa.w + xr4.w), at.w, vA);
        float vB = lrelu(xb.x + xr4.x) * at.x;
        vB = fmaf(lrelu(xb.y + xr4.y), at.y, vB);
        vB = fmaf(lrelu(xb.z + xr4.z), at.z, vB);
        vB = fmaf(lrelu(xb.w + xr4.w), at.w, vB);
        vA += __shfl_xor(vA, 1); vB += __shfl_xor(vB, 1);
        vA += __shfl_xor(vA, 2); vB += __shfl_xor(vB, 2);
        vA += __shfl_xor(vA, 4); vB += __shfl_xor(vB, 4);
        float pA = __expf(vA), pB = __expf(vB);
        l += pA + pB;
        ac0 = fmaf(pA, xa.x, ac0); ac0 = fmaf(pB, xb.x, ac0);
        ac1 = fmaf(pA, xa.y, ac1); ac1 = fmaf(pB, xb.y, ac1);
        ac2 = fmaf(pA, xa.z, ac2); ac2 = fmaf(pB, xb.z, ac2);
        ac3 = fmaf(pA, xa.w, ac3); ac3 = fmaf(pB, xb.w, ac3);
    }
    if (i < deg) {
        unsigned offA = (unsigned)sp[i] * DOUT + c0;
        float4 xa = *(const float4*)(xl2 + offA);
        float vA = lrelu(xa.x + xr4.x) * at.x;
        vA = fmaf(lrelu(xa.y + xr4.y), at.y, vA);
        vA = fmaf(lrelu(xa.z + xr4.z), at.z, vA);
        vA = fmaf(lrelu(xa.w + xr4.w), at.w, vA);
        vA += __shfl_xor(vA, 1);
        vA += __shfl_xor(vA, 2);
        vA += __shfl_xor(vA, 4);
        float pA = __expf(vA);
        l += pA;
        ac0 = fmaf(pA, xa.x, ac0); ac1 = fmaf(pA, xa.y, ac1);
        ac2 = fmaf(pA, xa.z, ac2); ac3 = fmaf(pA, xa.w, ac3);
    }
    const float inv = 1.f / (l + 1e-16f);
    const float4 bi = *(const float4*)(bias2 + c0);
    float o0 = ac0 * inv + bi.x;
    float o1 = ac1 * inv + bi.y;
    float o2 = ac2 * inv + bi.z;
    float o3 = ac3 * inv + bi.w;
    float mx = fmaxf(fmaxf(o0, o1), fmaxf(o2, o3));
    mx = fmaxf(mx, __shfl_xor(mx, 1));
    mx = fmaxf(mx, __shfl_xor(mx, 2));
    mx = fmaxf(mx, __shfl_xor(mx, 4));
    float se = __expf(o0 - mx) + __expf(o1 - mx) + __expf(o2 - mx) + __expf(o3 - mx);
    se += __shfl_xor(se, 1);
    se += __shfl_xor(se, 2);
    se += __shfl_xor(se, 4);
    float lse = mx + __logf(se);
    float4 ov; ov.x = o0; ov.y = o1; ov.z = o2; ov.w = o3;
    *(float4*)(out + (size_t)n * DOUT + c0) = ov;
    float4 lv; lv.x = o0 - lse; lv.y = o1 - lse; lv.z = o2 - lse; lv.w = o3 - lse;
    *(float4*)(out + (size_t)(NN + n) * DOUT + c0) = lv;
}

extern "C" void kernel_launch(void* const* d_in, const int* in_sizes, int n_in,
                              void* d_out, int out_size, void* d_ws, size_t ws_size,
                              hipStream_t stream)
{
    const float* x       = (const float*)d_in[0];
    const int*   ei      = (const int*)d_in[1];
    const float* Wl1     = (const float*)d_in[2];
    const float* bl1     = (const float*)d_in[3];
    const float* Wr1     = (const float*)d_in[4];
    const float* br1     = (const float*)d_in[5];
    const float* att1    = (const float*)d_in[6];
    const float* bias1   = (const float*)d_in[7];
    const float* gamma   = (const float*)d_in[8];
    const float* beta    = (const float*)d_in[9];
    const float* prelu_a = (const float*)d_in[10];
    const float* Wl2     = (const float*)d_in[11];
    const float* bl2     = (const float*)d_in[12];
    const float* Wr2     = (const float*)d_in[13];
    const float* br2     = (const float*)d_in[14];
    const float* att2    = (const float*)d_in[15];
    const float* bias2   = (const float*)d_in[16];
    const int* src = ei;
    const int* dst = ei + NE;

    // workspace layout (~112 MB)
    char* w = (char*)d_ws;
    unsigned short* xl1b = (unsigned short*)w;                  // 32 MB
    unsigned short* xr1b = xl1b + (size_t)NN * HID;             // 32 MB
    unsigned short* h1b  = xr1b + (size_t)NN * HID;             // 32 MB
    char* sm = w + 96000000ull;                                 // 16-aligned
    double* bn_sum = (double*)(sm + 0);                         // 2560 B
    double* bn_sq  = (double*)(sm + 2560);                      // 2560 B
    float* scale   = (float*)(sm + 5120);                       // 1280 B
    float* shift   = (float*)(sm + 6400);                       // 1280 B
    unsigned short* wl2t = (unsigned short*)(sm + 7680);        // 20480 B
    unsigned short* wr2t = (unsigned short*)(sm + 28160);       // 20480 B
    unsigned short* wlt1 = (unsigned short*)(sm + 48640);       // 81920 B
    unsigned short* wrt1 = (unsigned short*)(sm + 130560);      // 81920 B
    int* deg     = (int*)(sm + 212480);                         // 200000 B
    int* cursor  = (int*)(sm + 412480);                         // 200000 B
    int* sorted  = (int*)(sm + 612480);                         // 1.6 MB
    int* row_ptr = (int*)(sm + 2212480);                        // 200004 B
    int* tmp     = (int*)(sm + 2412484);                        // 200000 B
    int* bsum    = (int*)(sm + 2612484);                        // 256 B
    int* boff    = (int*)(sm + 2612740);                        // 256 B
    unsigned short* xb = (unsigned short*)(sm + 3000000);       // 12.8 MB (16-aligned)
    // layer-2 activation buffers reuse the (dead-after-agg1) xl1b region
    float* xl2 = (float*)w;
    float* xr2 = (float*)(w + (size_t)NN * DOUT * 4);

    hipMemsetAsync(deg, 0, NN * sizeof(int), stream);
    hipMemsetAsync(bn_sum, 0, 2 * HID * sizeof(double), stream);

    precast_x<<<(NN * DIN / 4 + 255) / 256, 256, 0, stream>>>(x, xb);
    precast_w1<<<(HID * DIN + 255) / 256, 256, 0, stream>>>(Wl1, Wr1, wlt1, wrt1);
    precast_w2<<<(HID * DOUT + 255) / 256, 256, 0, stream>>>(Wl2, Wr2, wl2t, wr2t);
    hist_kernel<<<(NE + 255) / 256, 256, 0, stream>>>(dst, deg);
    gemm1_kernel<<<7820, 256, 0, stream>>>(xb, wlt1, wrt1, bl1, br1, xl1b, xr1b);
    scan1_kernel<<<49, 1024, 0, stream>>>(deg, tmp, bsum);
    scan2_kernel<<<1, 64, 0, stream>>>(bsum, boff);
    scan3_kernel<<<49, 1024, 0, stream>>>(deg, tmp, boff, row_ptr, cursor);
    scatter_kernel<<<(NE + 255) / 256, 256, 0, stream>>>(src, dst, cursor, sorted);
    agg1_kernel<<<NN / 4, 320, 0, stream>>>(xl1b, xr1b, row_ptr, sorted, att1, bias1, h1b);
    bnstats_kernel<<<512, 320, 0, stream>>>(h1b, bn_sum, bn_sq);
    bnfinal_kernel<<<1, HID, 0, stream>>>(bn_sum, bn_sq, gamma, beta, scale, shift);
    gemm2_kernel<<<(NN + 63) / 64, 256, 0, stream>>>(h1b, scale, shift, prelu_a,
        wl2t, wr2t, bl2, br2, xl2, xr2);
    agg2_kernel<<<(NN + 31) / 32, 256, 0, stream>>>(xl2, xr2, row_ptr, sorted, att2, bias2,
        (float*)d_out);
}

// Round 10
// 424.814 us; speedup vs baseline: 1.3117x; 1.3117x over previous
//
#include <hip/hip_runtime.h>
#include <hip/hip_bf16.h>

#define NN 50000
#define NE 400000
#define DIN 128
#define DH 32
#define NH 10
#define HID 320
#define DOUT 32
#define NEG_SLOPE 0.2f
#define EPS_BN 1e-5f

typedef __attribute__((ext_vector_type(8))) short short8;
typedef __attribute__((ext_vector_type(4))) float f32x4;

__device__ inline unsigned short f2bf(float f) {
    unsigned int u = __float_as_uint(f);
    u += 0x7fffu + ((u >> 16) & 1u);
    return (unsigned short)(u >> 16);
}
__device__ inline float bf2f(unsigned short u) {
    return __uint_as_float(((unsigned int)u) << 16);
}
__device__ inline float bflo(unsigned int u) { return __uint_as_float(u << 16); }
__device__ inline float bfhi(unsigned int u) { return __uint_as_float(u & 0xffff0000u); }
__device__ inline float lrelu(float x) { return fmaxf(x, NEG_SLOPE * x); }

// ---------------- precasts ----------------
__global__ __launch_bounds__(256) void precast_x(const float* __restrict__ x,
        unsigned short* __restrict__ xb) {
    int i = blockIdx.x * 256 + threadIdx.x;          // over NN*DIN/4
    if (i < NN * DIN / 4) {
        float4 v = *(const float4*)(x + (size_t)i * 4);
        ushort4 s;
        s.x = f2bf(v.x); s.y = f2bf(v.y); s.z = f2bf(v.z); s.w = f2bf(v.w);
        *(ushort4*)(xb + (size_t)i * 4) = s;
    }
}

__global__ void precast_w1(const float* __restrict__ Wl, const float* __restrict__ Wr,
        unsigned short* __restrict__ wlt, unsigned short* __restrict__ wrt) {
    int idx = blockIdx.x * 256 + threadIdx.x;        // over HID*DIN = 40960
    if (idx < HID * DIN) {
        int c = idx >> 7, k = idx & 127;
        wlt[idx] = f2bf(Wl[(size_t)k * HID + c]);
        wrt[idx] = f2bf(Wr[(size_t)k * HID + c]);
    }
}

__global__ void precast_w2(const float* __restrict__ Wl2, const float* __restrict__ Wr2,
        unsigned short* __restrict__ wl2t, unsigned short* __restrict__ wr2t) {
    int idx = blockIdx.x * 256 + threadIdx.x;        // over HID*DOUT = 10240
    if (idx < HID * DOUT) {
        int c = idx / HID, k = idx - c * HID;
        wl2t[idx] = f2bf(Wl2[k * DOUT + c]);
        wr2t[idx] = f2bf(Wr2[k * DOUT + c]);
    }
}

// ---------------- GEMM1: A staged in LDS (bf16 copy), W direct from global (L1) ----------
__global__ __launch_bounds__(256) void gemm1_kernel(
    const unsigned short* __restrict__ xb,
    const unsigned short* __restrict__ wlt, const unsigned short* __restrict__ wrt,
    const float* __restrict__ bl, const float* __restrict__ br,
    unsigned short* __restrict__ xl1, unsigned short* __restrict__ xr1)
{
    __shared__ short xs[64 * 128];   // bf16 A tile, XOR-swizzled 16B units
    // bijective XCD chunking: 7820 = 8*977+4 -> xcd<4 own 978 tiles, else 977
    int b = blockIdx.x;
    int xcd = b & 7, j = b >> 3;
    int base = (xcd < 4) ? xcd * 978 : 3912 + (xcd - 4) * 977;
    int t = base + j;
    int r0 = (t / 10) * 64;
    int c0 = (t % 10) * 32;

    const int tid = threadIdx.x;
    // stage A: 64 rows x 128 ch = 2048 ushort4 (plain copy, no converts)
    for (int i = tid; i < 2048; i += 256) {
        int rr = i >> 5;
        int u4 = (i & 31) << 2;                  // ushort offset within row
        ushort4 v = make_ushort4(0, 0, 0, 0);
        if (r0 + rr < NN) v = *(const ushort4*)(xb + (size_t)(r0 + rr) * DIN + u4);
        int u = (rr * 128 + u4) ^ ((rr & 7) << 3);
        *(ushort4*)&xs[u] = v;
    }
    __syncthreads();

    const int w = tid >> 6, lane = tid & 63;
    const int row16 = lane & 15;
    const int kgrp = (lane >> 4) << 3;
    const int arow = w * 16 + row16;
    const unsigned short* bLp = wlt + (size_t)(c0 + row16) * DIN + kgrp;
    const unsigned short* bRp = wrt + (size_t)(c0 + row16) * DIN + kgrp;

    f32x4 acc00 = {}, acc01 = {}, acc10 = {}, acc11 = {};
    #pragma unroll
    for (int kk = 0; kk < 4; ++kk) {
        int au = (arow * 128 + kk * 32 + kgrp) ^ ((arow & 7) << 3);
        short8 a = *(short8*)&xs[au];
        short8 bL0 = *(const short8*)(bLp + kk * 32);
        short8 bL1 = *(const short8*)(bLp + 16 * DIN + kk * 32);
        short8 bR0 = *(const short8*)(bRp + kk * 32);
        short8 bR1 = *(const short8*)(bRp + 16 * DIN + kk * 32);
        acc00 = __builtin_amdgcn_mfma_f32_16x16x32_bf16(a, bL0, acc00, 0, 0, 0);
        acc01 = __builtin_amdgcn_mfma_f32_16x16x32_bf16(a, bL1, acc01, 0, 0, 0);
        acc10 = __builtin_amdgcn_mfma_f32_16x16x32_bf16(a, bR0, acc10, 0, 0, 0);
        acc11 = __builtin_amdgcn_mfma_f32_16x16x32_bf16(a, bR1, acc11, 0, 0, 0);
    }
    const int orow = r0 + w * 16 + ((lane >> 4) << 2);
    #pragma unroll
    for (int cf = 0; cf < 2; ++cf) {
        const int col = c0 + cf * 16 + row16;
        const float blv = bl[col], brv = br[col];
        const f32x4 aL = cf ? acc01 : acc00;
        const f32x4 aR = cf ? acc11 : acc10;
        #pragma unroll
        for (int reg = 0; reg < 4; ++reg) {
            int row = orow + reg;
            if (row < NN) {
                xl1[(size_t)row * HID + col] = f2bf(aL[reg] + blv);
                xr1[(size_t)row * HID + col] = f2bf(aR[reg] + brv);
            }
        }
    }
}

// ---------------- CSR build ----------------
__global__ void hist_kernel(const int* __restrict__ dst, int* __restrict__ deg) {
    int e = blockIdx.x * blockDim.x + threadIdx.x;
    if (e < NE) atomicAdd(&deg[dst[e]], 1);
}

// 3-phase hierarchical scan: 49 blocks x 1024
__global__ __launch_bounds__(1024) void scan1_kernel(const int* __restrict__ deg,
        int* __restrict__ tmp, int* __restrict__ bsum) {
    __shared__ int s[1024];
    const int tid = threadIdx.x;
    int i = blockIdx.x * 1024 + tid;
    int v = (i < NN) ? deg[i] : 0;
    s[tid] = v;
    __syncthreads();
    for (int off = 1; off < 1024; off <<= 1) {
        int u = (tid >= off) ? s[tid - off] : 0;
        __syncthreads();
        s[tid] += u;
        __syncthreads();
    }
    if (i < NN) tmp[i] = s[tid];
    if (tid == 1023) bsum[blockIdx.x] = s[1023];
}

__global__ void scan2_kernel(const int* __restrict__ bsum, int* __restrict__ boff) {
    int lane = threadIdx.x;                  // 64 threads, 1 wave
    int v = (lane < 49) ? bsum[lane] : 0;
    for (int off = 1; off < 64; off <<= 1) {
        int u = __shfl_up(v, off);
        if (lane >= off) v += u;
    }
    int excl = __shfl_up(v, 1);
    if (lane == 0) excl = 0;
    if (lane < 49) boff[lane] = excl;
}

__global__ __launch_bounds__(1024) void scan3_kernel(const int* __restrict__ deg,
        const int* __restrict__ tmp, const int* __restrict__ boff,
        int* __restrict__ row_ptr, int* __restrict__ cursor) {
    int i = blockIdx.x * 1024 + threadIdx.x;
    if (i < NN) {
        int incl = tmp[i] + boff[blockIdx.x];
        int st = incl - deg[i];
        row_ptr[i] = st;
        cursor[i] = st;
        if (i == NN - 1) row_ptr[NN] = incl;
    }
}

__global__ void scatter_kernel(const int* __restrict__ src, const int* __restrict__ dst,
        int* __restrict__ cursor, int* __restrict__ sorted_src) {
    int e = blockIdx.x * blockDim.x + threadIdx.x;
    if (e < NE) {
        int d = dst[e];
        int p = atomicAdd(&cursor[d], 1);
        sorted_src[p] = src[e];
    }
}

// ---------------- Layer-1 aggregation: 4 nodes/block, 8 lanes/head, 4 ch/lane -----------
__global__ __launch_bounds__(320) void agg1_kernel(
    const unsigned short* __restrict__ xl1, const unsigned short* __restrict__ xr1,
    const int* __restrict__ row_ptr, const int* __restrict__ sorted_src,
    const float* __restrict__ att1, const float* __restrict__ bias1,
    unsigned short* __restrict__ h1b)
{
    const int t = threadIdx.x;
    const int nsub = t / 80;
    const int r = t - nsub * 80;
    const int h = r >> 3;
    const int l8 = r & 7;
    const int c0 = h * 32 + l8 * 4;
    const int n = blockIdx.x * 4 + nsub;

    const float4 at = *(const float4*)(att1 + c0);
    const unsigned rbase = (unsigned)n * HID + c0;
    uint2 xr4 = *(const uint2*)(xr1 + rbase);
    const float xr0 = bflo(xr4.x), xr1f = bfhi(xr4.x);
    const float xr2 = bflo(xr4.y), xr3 = bfhi(xr4.y);

    const int rp = row_ptr[n];
    const int deg = row_ptr[n + 1] - rp;
    const int* sp = sorted_src + rp;

    float l = 0.f, ac0 = 0.f, ac1 = 0.f, ac2 = 0.f, ac3 = 0.f;
    int i = 0;
    for (; i + 2 <= deg; i += 2) {
        unsigned offA = (unsigned)sp[i] * HID + c0;
        unsigned offB = (unsigned)sp[i + 1] * HID + c0;
        uint2 ua = *(const uint2*)(xl1 + offA);
        uint2 ub = *(const uint2*)(xl1 + offB);
        float xA0 = bflo(ua.x), xA1 = bfhi(ua.x), xA2 = bflo(ua.y), xA3 = bfhi(ua.y);
        float xB0 = bflo(ub.x), xB1 = bfhi(ub.x), xB2 = bflo(ub.y), xB3 = bfhi(ub.y);
        float vA = lrelu(xA0 + xr0) * at.x;
        vA = fmaf(lrelu(xA1 + xr1f), at.y, vA);
        vA = fmaf(lrelu(xA2 + xr2), at.z, vA);
        vA = fmaf(lrelu(xA3 + xr3), at.w, vA);
        float vB = lrelu(xB0 + xr0) * at.x;
        vB = fmaf(lrelu(xB1 + xr1f), at.y, vB);
        vB = fmaf(lrelu(xB2 + xr2), at.z, vB);
        vB = fmaf(lrelu(xB3 + xr3), at.w, vB);
        vA += __shfl_xor(vA, 1); vB += __shfl_xor(vB, 1);
        vA += __shfl_xor(vA, 2); vB += __shfl_xor(vB, 2);
        vA += __shfl_xor(vA, 4); vB += __shfl_xor(vB, 4);
        float pA = __expf(vA), pB = __expf(vB);
        l += pA + pB;
        ac0 = fmaf(pA, xA0, ac0); ac0 = fmaf(pB, xB0, ac0);
        ac1 = fmaf(pA, xA1, ac1); ac1 = fmaf(pB, xB1, ac1);
        ac2 = fmaf(pA, xA2, ac2); ac2 = fmaf(pB, xB2, ac2);
        ac3 = fmaf(pA, xA3, ac3); ac3 = fmaf(pB, xB3, ac3);
    }
    if (i < deg) {
        unsigned offA = (unsigned)sp[i] * HID + c0;
        uint2 ua = *(const uint2*)(xl1 + offA);
        float xA0 = bflo(ua.x), xA1 = bfhi(ua.x), xA2 = bflo(ua.y), xA3 = bfhi(ua.y);
        float vA = lrelu(xA0 + xr0) * at.x;
        vA = fmaf(lrelu(xA1 + xr1f), at.y, vA);
        vA = fmaf(lrelu(xA2 + xr2), at.z, vA);
        vA = fmaf(lrelu(xA3 + xr3), at.w, vA);
        vA += __shfl_xor(vA, 1);
        vA += __shfl_xor(vA, 2);
        vA += __shfl_xor(vA, 4);
        float pA = __expf(vA);
        l += pA;
        ac0 = fmaf(pA, xA0, ac0); ac1 = fmaf(pA, xA1, ac1);
        ac2 = fmaf(pA, xA2, ac2); ac3 = fmaf(pA, xA3, ac3);
    }
    const float inv = 1.f / (l + 1e-16f);
    const float4 bi = *(const float4*)(bias1 + c0);
    uint2 outp;
    outp.x = (unsigned)f2bf(ac0 * inv + bi.x) | ((unsigned)f2bf(ac1 * inv + bi.y) << 16);
    outp.y = (unsigned)f2bf(ac2 * inv + bi.z) | ((unsigned)f2bf(ac3 * inv + bi.w) << 16);
    *(uint2*)(h1b + rbase) = outp;
}

// ---------------- BatchNorm: two-stage, atomic-free ----------------
__global__ __launch_bounds__(320) void bnpart_kernel(const unsigned short* __restrict__ h1b,
        float* __restrict__ ps, float* __restrict__ pq) {
    const int c = threadIdx.x;
    float s = 0.f, q = 0.f;
    for (int n = blockIdx.x; n < NN; n += gridDim.x) {
        float v = bf2f(h1b[(size_t)n * HID + c]);
        s += v;
        q = fmaf(v, v, q);
    }
    ps[(size_t)blockIdx.x * HID + c] = s;
    pq[(size_t)blockIdx.x * HID + c] = q;
}

__global__ void bnfinal_kernel(const float* __restrict__ ps, const float* __restrict__ pq,
        const float* __restrict__ gamma, const float* __restrict__ beta,
        float* __restrict__ scale, float* __restrict__ shift) {
    int c = threadIdx.x;
    double S = 0.0, Q = 0.0;
    for (int b = 0; b < 1024; ++b) {
        S += (double)ps[(size_t)b * HID + c];
        Q += (double)pq[(size_t)b * HID + c];
    }
    double mean = S / (double)NN;
    double var  = Q / (double)NN - mean * mean;
    float sc = gamma[c] * rsqrtf((float)var + EPS_BN);
    scale[c] = sc;
    shift[c] = beta[c] - (float)mean * sc;
}

// ---------------- GEMM2 (MFMA bf16) fused BN+PReLU: h[NN,320] @ [320,32] -> xl2, xr2 -----
__global__ __launch_bounds__(256) void gemm2_kernel(
    const unsigned short* __restrict__ h1b,
    const float* __restrict__ scale, const float* __restrict__ shift,
    const float* __restrict__ prelu_a,
    const unsigned short* __restrict__ wl2t, const unsigned short* __restrict__ wr2t,
    const float* __restrict__ bl2, const float* __restrict__ br2,
    float* __restrict__ xl2, float* __restrict__ xr2)
{
    __shared__ short hs[64 * 320];   // transformed rows, bf16, XOR-swizzled
    const int tid = threadIdx.x;
    const int r0 = blockIdx.x * 64;
    const float a = prelu_a[0];
    for (int f = tid; f < 5120; f += 256) {
        int e = f << 2;
        int rr = e / 320;
        int cc = e - rr * 320;
        ushort4 hv = make_ushort4(0, 0, 0, 0);
        if (r0 + rr < NN) hv = *(const ushort4*)(h1b + (size_t)(r0 + rr) * HID + cc);
        float4 sc = *(const float4*)(scale + cc);
        float4 sh = *(const float4*)(shift + cc);
        float o0 = bf2f(hv.x) * sc.x + sh.x; o0 = (o0 >= 0.f) ? o0 : a * o0;
        float o1 = bf2f(hv.y) * sc.y + sh.y; o1 = (o1 >= 0.f) ? o1 : a * o1;
        float o2 = bf2f(hv.z) * sc.z + sh.z; o2 = (o2 >= 0.f) ? o2 : a * o2;
        float o3 = bf2f(hv.w) * sc.w + sh.w; o3 = (o3 >= 0.f) ? o3 : a * o3;
        short4 s;
        s.x = (short)f2bf(o0); s.y = (short)f2bf(o1);
        s.z = (short)f2bf(o2); s.w = (short)f2bf(o3);
        int u = (rr * 320 + cc) ^ ((rr & 7) << 3);
        *(short4*)&hs[u] = s;
    }
    __syncthreads();

    const int w = tid >> 6, lane = tid & 63;
    const int arow = w * 16 + (lane & 15);
    const int kgrp = (lane >> 4) << 3;
    const int bcol = lane & 15;
    f32x4 acc00 = {}, acc01 = {}, acc10 = {}, acc11 = {};
    #pragma unroll
    for (int kk = 0; kk < 10; ++kk) {
        int au = (arow * 320 + kk * 32 + kgrp) ^ ((arow & 7) << 3);
        short8 afr = *(short8*)&hs[au];
        const int ko = kk * 32 + kgrp;
        short8 bL0 = *(const short8*)(wl2t + bcol * HID + ko);
        short8 bL1 = *(const short8*)(wl2t + (16 + bcol) * HID + ko);
        short8 bR0 = *(const short8*)(wr2t + bcol * HID + ko);
        short8 bR1 = *(const short8*)(wr2t + (16 + bcol) * HID + ko);
        acc00 = __builtin_amdgcn_mfma_f32_16x16x32_bf16(afr, bL0, acc00, 0, 0, 0);
        acc01 = __builtin_amdgcn_mfma_f32_16x16x32_bf16(afr, bL1, acc01, 0, 0, 0);
        acc10 = __builtin_amdgcn_mfma_f32_16x16x32_bf16(afr, bR0, acc10, 0, 0, 0);
        acc11 = __builtin_amdgcn_mfma_f32_16x16x32_bf16(afr, bR1, acc11, 0, 0, 0);
    }
    const int orow = r0 + w * 16 + ((lane >> 4) << 2);
    #pragma unroll
    for (int cf = 0; cf < 2; ++cf) {
        const int col = cf * 16 + bcol;
        const float blv = bl2[col], brv = br2[col];
        const f32x4 aL = cf ? acc01 : acc00;
        const f32x4 aR = cf ? acc11 : acc10;
        #pragma unroll
        for (int reg = 0; reg < 4; ++reg) {
            int row = orow + reg;
            if (row < NN) {
                xl2[(size_t)row * DOUT + col] = aL[reg] + blv;
                xr2[(size_t)row * DOUT + col] = aR[reg] + brv;
            }
        }
    }
}

// ---------------- Layer-2 aggregation: 32 nodes/block, 8 lanes/node, 4 ch/lane ----------
__global__ __launch_bounds__(256) void agg2_kernel(
    const float* __restrict__ xl2, const float* __restrict__ xr2,
    const int* __restrict__ row_ptr, const int* __restrict__ sorted_src,
    const float* __restrict__ att2, const float* __restrict__ bias2,
    float* __restrict__ out)
{
    const int t = threadIdx.x;
    const int nsub = t >> 3;
    const int l8 = t & 7;
    const int c0 = l8 * 4;
    const int n = blockIdx.x * 32 + nsub;
    if (n >= NN) return;

    const float4 at = *(const float4*)(att2 + c0);
    const float4 xr4 = *(const float4*)(xr2 + (size_t)n * DOUT + c0);
    const int rp = row_ptr[n];
    const int deg = row_ptr[n + 1] - rp;
    const int* sp = sorted_src + rp;

    float l = 0.f, ac0 = 0.f, ac1 = 0.f, ac2 = 0.f, ac3 = 0.f;
    int i = 0;
    for (; i + 2 <= deg; i += 2) {
        unsigned offA = (unsigned)sp[i] * DOUT + c0;
        unsigned offB = (unsigned)sp[i + 1] * DOUT + c0;
        float4 xa = *(const float4*)(xl2 + offA);
        float4 xb = *(const float4*)(xl2 + offB);
        float vA = lrelu(xa.x + xr4.x) * at.x;
        vA = fmaf(lrelu(xa.y + xr4.y), at.y, vA);
        vA = fmaf(lrelu(xa.z + xr4.z), at.z, vA);
        vA = fmaf(lrelu(xa.w + xr4.w), at.w, vA);
        float vB = lrelu(xb.x + xr4.x) * at.x;
        vB = fmaf(lrelu(xb.y + xr4.y), at.y, vB);
        vB = fmaf(lrelu(xb.z + xr4.z), at.z, vB);
        vB = fmaf(lrelu(xb.w + xr4.w), at.w, vB);
        vA += __shfl_xor(vA, 1); vB += __shfl_xor(vB, 1);
        vA += __shfl_xor(vA, 2); vB += __shfl_xor(vB, 2);
        vA += __shfl_xor(vA, 4); vB += __shfl_xor(vB, 4);
        float pA = __expf(vA), pB = __expf(vB);
        l += pA + pB;
        ac0 = fmaf(pA, xa.x, ac0); ac0 = fmaf(pB, xb.x, ac0);
        ac1 = fmaf(pA, xa.y, ac1); ac1 = fmaf(pB, xb.y, ac1);
        ac2 = fmaf(pA, xa.z, ac2); ac2 = fmaf(pB, xb.z, ac2);
        ac3 = fmaf(pA, xa.w, ac3); ac3 = fmaf(pB, xb.w, ac3);
    }
    if (i < deg) {
        unsigned offA = (unsigned)sp[i] * DOUT + c0;
        float4 xa = *(const float4*)(xl2 + offA);
        float vA = lrelu(xa.x + xr4.x) * at.x;
        vA = fmaf(lrelu(xa.y + xr4.y), at.y, vA);
        vA = fmaf(lrelu(xa.z + xr4.z), at.z, vA);
        vA = fmaf(lrelu(xa.w + xr4.w), at.w, vA);
        vA += __shfl_xor(vA, 1);
        vA += __shfl_xor(vA, 2);
        vA += __shfl_xor(vA, 4);
        float pA = __expf(vA);
        l += pA;
        ac0 = fmaf(pA, xa.x, ac0); ac1 = fmaf(pA, xa.y, ac1);
        ac2 = fmaf(pA, xa.z, ac2); ac3 = fmaf(pA, xa.w, ac3);
    }
    const float inv = 1.f / (l + 1e-16f);
    const float4 bi = *(const float4*)(bias2 + c0);
    float o0 = ac0 * inv + bi.x;
    float o1 = ac1 * inv + bi.y;
    float o2 = ac2 * inv + bi.z;
    float o3 = ac3 * inv + bi.w;
    float mx = fmaxf(fmaxf(o0, o1), fmaxf(o2, o3));
    mx = fmaxf(mx, __shfl_xor(mx, 1));
    mx = fmaxf(mx, __shfl_xor(mx, 2));
    mx = fmaxf(mx, __shfl_xor(mx, 4));
    float se = __expf(o0 - mx) + __expf(o1 - mx) + __expf(o2 - mx) + __expf(o3 - mx);
    se += __shfl_xor(se, 1);
    se += __shfl_xor(se, 2);
    se += __shfl_xor(se, 4);
    float lse = mx + __logf(se);
    float4 ov; ov.x = o0; ov.y = o1; ov.z = o2; ov.w = o3;
    *(float4*)(out + (size_t)n * DOUT + c0) = ov;
    float4 lv; lv.x = o0 - lse; lv.y = o1 - lse; lv.z = o2 - lse; lv.w = o3 - lse;
    *(float4*)(out + (size_t)(NN + n) * DOUT + c0) = lv;
}

extern "C" void kernel_launch(void* const* d_in, const int* in_sizes, int n_in,
                              void* d_out, int out_size, void* d_ws, size_t ws_size,
                              hipStream_t stream)
{
    const float* x       = (const float*)d_in[0];
    const int*   ei      = (const int*)d_in[1];
    const float* Wl1     = (const float*)d_in[2];
    const float* bl1     = (const float*)d_in[3];
    const float* Wr1     = (const float*)d_in[4];
    const float* br1     = (const float*)d_in[5];
    const float* att1    = (const float*)d_in[6];
    const float* bias1   = (const float*)d_in[7];
    const float* gamma   = (const float*)d_in[8];
    const float* beta    = (const float*)d_in[9];
    const float* prelu_a = (const float*)d_in[10];
    const float* Wl2     = (const float*)d_in[11];
    const float* bl2     = (const float*)d_in[12];
    const float* Wr2     = (const float*)d_in[13];
    const float* br2     = (const float*)d_in[14];
    const float* att2    = (const float*)d_in[15];
    const float* bias2   = (const float*)d_in[16];
    const int* src = ei;
    const int* dst = ei + NE;

    // workspace layout (~119 MB)
    char* w = (char*)d_ws;
    unsigned short* xl1b = (unsigned short*)w;                  // 32 MB
    unsigned short* xr1b = xl1b + (size_t)NN * HID;             // 32 MB
    unsigned short* h1b  = xr1b + (size_t)NN * HID;             // 32 MB
    char* sm = w + 96000000ull;                                 // 16-aligned
    float* scale   = (float*)(sm + 5120);                       // 1280 B
    float* shift   = (float*)(sm + 6400);                       // 1280 B
    unsigned short* wl2t = (unsigned short*)(sm + 7680);        // 20480 B
    unsigned short* wr2t = (unsigned short*)(sm + 28160);       // 20480 B
    unsigned short* wlt1 = (unsigned short*)(sm + 48640);       // 81920 B
    unsigned short* wrt1 = (unsigned short*)(sm + 130560);      // 81920 B
    int* deg     = (int*)(sm + 212480);                         // 200000 B
    int* cursor  = (int*)(sm + 412480);                         // 200000 B
    int* sorted  = (int*)(sm + 612480);                         // 1.6 MB
    int* row_ptr = (int*)(sm + 2212480);                        // 200004 B
    int* tmp     = (int*)(sm + 2412484);                        // 200000 B
    int* bsum    = (int*)(sm + 2612484);                        // 256 B
    int* boff    = (int*)(sm + 2612740);                        // 256 B
    unsigned short* xb = (unsigned short*)(sm + 3000000);       // 12.8 MB
    float* bn_ps = (float*)(sm + 16000000);                     // 1024*320*4 = 1.31 MB
    float* bn_pq = (float*)(sm + 18000000);                     // 1.31 MB
    // layer-2 activation buffers reuse the (dead-after-agg1) xl1b region
    float* xl2 = (float*)w;
    float* xr2 = (float*)(w + (size_t)NN * DOUT * 4);

    hipMemsetAsync(deg, 0, NN * sizeof(int), stream);

    precast_x<<<(NN * DIN / 4 + 255) / 256, 256, 0, stream>>>(x, xb);
    precast_w1<<<(HID * DIN + 255) / 256, 256, 0, stream>>>(Wl1, Wr1, wlt1, wrt1);
    precast_w2<<<(HID * DOUT + 255) / 256, 256, 0, stream>>>(Wl2, Wr2, wl2t, wr2t);
    hist_kernel<<<(NE + 255) / 256, 256, 0, stream>>>(dst, deg);
    gemm1_kernel<<<7820, 256, 0, stream>>>(xb, wlt1, wrt1, bl1, br1, xl1b, xr1b);
    scan1_kernel<<<49, 1024, 0, stream>>>(deg, tmp, bsum);
    scan2_kernel<<<1, 64, 0, stream>>>(bsum, boff);
    scan3_kernel<<<49, 1024, 0, stream>>>(deg, tmp, boff, row_ptr, cursor);
    scatter_kernel<<<(NE + 255) / 256, 256, 0, stream>>>(src, dst, cursor, sorted);
    agg1_kernel<<<NN / 4, 320, 0, stream>>>(xl1b, xr1b, row_ptr, sorted, att1, bias1, h1b);
    bnpart_kernel<<<1024, HID, 0, stream>>>(h1b, bn_ps, bn_pq);
    bnfinal_kernel<<<1, HID, 0, stream>>>(bn_ps, bn_pq, gamma, beta, scale, shift);
    gemm2_kernel<<<(NN + 63) / 64, 256, 0, stream>>>(h1b, scale, shift, prelu_a,
        wl2t, wr2t, bl2, br2, xl2, xr2);
    agg2_kernel<<<(NN + 31) / 32, 256, 0, stream>>>(xl2, xr2, row_ptr, sorted, att2, bias2,
        (float*)d_out);
}